// Round 10
// baseline (276.984 us; speedup 1.0000x reference)
//
#include <hip/hip_runtime.h>
#include <math.h>

// ---------------------------------------------------------------------------
// AttentionBlock: GroupNorm(32) -> QKV proj -> MHA(8 heads) -> out proj
// B=16, C=512, L=1024, group=16ch, head ch=64.
// Round 16b (compile fix: cvt_pkrtz returns __fp16x2, union member adjusted):
//           attn ONE barrier per s-tile (was 2). V double-buffered (reg
//           path), K double-buffered (async global_load_lds). Schedule:
//           body(i) = dsWriteV(i)->vb[i&1]; barrier; issue asyncK(i+1)+
//           Vload(i+1); QK(kb[i&1]); softmax; PV(vb[i&1]). Barrier of iter i
//           proves all waves retired iter i-1 -> prefetch targets have no
//           readers; implicit vmcnt(0) drains 1-iter-old loads (free).
//           Literal buffer pointers via unroll-by-2 (R8-proven codegen).
// ---------------------------------------------------------------------------

typedef _Float16 f16x8 __attribute__((ext_vector_type(8)));
typedef _Float16 f16x4 __attribute__((ext_vector_type(4)));
typedef __fp16 fp16x2 __attribute__((ext_vector_type(2)));  // cvt_pkrtz type
typedef float f32x4 __attribute__((ext_vector_type(4)));

// NOTE: legacy K=16 fp16 MFMA builtin has NO underscore before f16.
#define MFMA_K16(A, B, C) __builtin_amdgcn_mfma_f32_16x16x16f16(A, B, C, 0, 0, 0)

// async 16B/lane global->LDS copy. LDS dest is WAVE-UNIFORM base; HW places
// lane i at base + i*16. Global src is per-lane.
__device__ __forceinline__ void async_cp16(const void* g, void* l) {
  __builtin_amdgcn_global_load_lds(
      (const __attribute__((address_space(1))) void*)g,
      (__attribute__((address_space(3))) void*)l, 16, 0, 0);
}

// ------------------------- weight fp32 -> fp16 (both, one launch) -----------
__global__ __launch_bounds__(256) void cvt_weights(
    const float* __restrict__ wq, const float* __restrict__ wp,
    _Float16* __restrict__ dq, _Float16* __restrict__ dp) {
  int i = blockIdx.x * 256 + threadIdx.x;
  if (i < 196608) {
    float4 v = ((const float4*)wq)[i];
    f16x4 o = {(_Float16)v.x, (_Float16)v.y, (_Float16)v.z, (_Float16)v.w};
    *(f16x4*)&dq[(size_t)i * 4] = o;
  } else {
    int j = i - 196608;  // < 65536 by grid sizing
    float4 v = ((const float4*)wp)[j];
    f16x4 o = {(_Float16)v.x, (_Float16)v.y, (_Float16)v.z, (_Float16)v.w};
    *(f16x4*)&dp[(size_t)j * 4] = o;
  }
}

// ------------------------- GroupNorm (writes hT [b][l][c] fp16) -------------
__global__ __launch_bounds__(256) void gn_kernel(
    const float* __restrict__ x, const float* __restrict__ gw,
    const float* __restrict__ gb, _Float16* __restrict__ hT) {
  const int b = blockIdx.x >> 5;
  const int g = blockIdx.x & 31;
  const size_t base = ((size_t)(b * 512 + g * 16)) * 1024;
  const float4* xp = (const float4*)(x + base);
  const int tid = threadIdx.x;

  float4 vals[16];
  float s = 0.f, sq = 0.f;
#pragma unroll
  for (int r = 0; r < 16; ++r) {
    float4 v = xp[tid + 256 * r];
    vals[r] = v;
    s += v.x + v.y + v.z + v.w;
    sq += v.x * v.x + v.y * v.y + v.z * v.z + v.w * v.w;
  }
  __shared__ float rs[256];
  __shared__ float rq[256];
  rs[tid] = s;
  rq[tid] = sq;
  __syncthreads();
  for (int off = 128; off > 0; off >>= 1) {
    if (tid < off) {
      rs[tid] += rs[tid + off];
      rq[tid] += rq[tid + off];
    }
    __syncthreads();
  }
  const float mean = rs[0] * (1.f / 16384.f);
  const float var = rq[0] * (1.f / 16384.f) - mean * mean;
  const float rinv = rsqrtf(var + 1e-5f);
#pragma unroll
  for (int r = 0; r < 16; ++r) {
    const int c = g * 16 + r;
    const float wc = gw[c] * rinv;
    const float bc = gb[c] - mean * wc;
    vals[r].x = vals[r].x * wc + bc;
    vals[r].y = vals[r].y * wc + bc;
    vals[r].z = vals[r].z * wc + bc;
    vals[r].w = vals[r].w * wc + bc;
  }
  _Float16* hb = hT + ((size_t)b * 1024 + tid * 4) * 512 + g * 16;
#pragma unroll
  for (int li = 0; li < 4; ++li) {
    f16x8 o0, o1;
#pragma unroll
    for (int r = 0; r < 8; ++r) {
      float v0 = li == 0 ? vals[r].x : li == 1 ? vals[r].y
                 : li == 2 ? vals[r].z : vals[r].w;
      float v1 = li == 0 ? vals[8 + r].x : li == 1 ? vals[8 + r].y
                 : li == 2 ? vals[8 + r].z : vals[8 + r].w;
      o0[r] = (_Float16)v0;
      o1[r] = (_Float16)v1;
    }
    *(f16x8*)(hb + (size_t)li * 512) = o0;
    *(f16x8*)(hb + (size_t)li * 512 + 8) = o1;
  }
}

// ------------------------- fp16 MFMA GEMM, BK=64 single buffer --------------
// C[m][n] = sum_k A[m][k]*B[n][k] (+bias), stored TRANSPOSED: Out[n][m].
// 128x128 tile, BK=64, 8 K-steps (K=512). LDS rows are 128B linear (async
// copy needs contiguous dest); bank uniformity via XOR source swizzle:
// LDS phys 16B-chunk p of row r holds logical chunk p ^ (r&7); fragment
// reads apply the same XOR.
// Epilogue: C-frags (+bias) -> LDS [n][m] tile -> coalesced row stores.
template <typename OutT, bool BIAS_ON_M>
__global__ __launch_bounds__(256) void gemm_tn(
    const _Float16* __restrict__ A, const _Float16* __restrict__ B,
    const float* __restrict__ bias, OutT* __restrict__ Out,
    int M, int N, int K, long sA, long sB) {
  // smem: As(16K) Bs(16K) = 32K | epilogue T (34.8K)
  __shared__ __align__(16) char smem[34816];
  _Float16* As = (_Float16*)smem;
  _Float16* Bs = As + 128 * 64;
  const int tid = threadIdx.x;
  const int w = tid >> 6, lane = tid & 63;
  const int lx = lane & 15, quad = lane >> 4;
  const int wm = w >> 1, wn = w & 1;
  const int bn = blockIdx.x * 128, bm = blockIdx.y * 128;
  const int z = blockIdx.z;

  // staging geometry: row = w*32 + j*8 + (lane>>3); phys chunk = lane&7;
  // global logical chunk = (lane&7) ^ ((lane>>3)&7)  [row&7 == (lane>>3)&7]
  const int srow = w * 32 + (lane >> 3);
  const int scol = (((lane & 7) ^ ((lane >> 3) & 7)) * 8);
  const _Float16* Ag = A + (size_t)z * sA + (size_t)(bm + srow) * K + scol;
  const _Float16* Bg = B + (size_t)z * sB + (size_t)(bn + srow) * K + scol;

  f32x4 acc[4][4];
#pragma unroll
  for (int i = 0; i < 4; ++i)
#pragma unroll
    for (int j = 0; j < 4; ++j) acc[i][j] = (f32x4){0.f, 0.f, 0.f, 0.f};

  const int xa = lx & 7;  // row&7 for this lane's fragment rows

  for (int k0 = 0; k0 < K; k0 += 64) {
    __syncthreads();  // prior step's fragment reads complete
#pragma unroll
    for (int j = 0; j < 4; ++j) {
      async_cp16(Ag + (size_t)j * 8 * K + k0, &As[(w * 32 + j * 8) * 64]);
      async_cp16(Bg + (size_t)j * 8 * K + k0, &Bs[(w * 32 + j * 8) * 64]);
    }
    __syncthreads();  // implicit vmcnt(0): buffer ready
#pragma unroll
    for (int h = 0; h < 2; ++h) {
      f16x8 af[4], bf[4];
#pragma unroll
      for (int mt = 0; mt < 4; ++mt)
        af[mt] = *(const f16x8*)&As[(wm * 64 + mt * 16 + lx) * 64 +
                                    ((h * 4 + quad) ^ xa) * 8];
#pragma unroll
      for (int nt = 0; nt < 4; ++nt)
        bf[nt] = *(const f16x8*)&Bs[(wn * 64 + nt * 16 + lx) * 64 +
                                    ((h * 4 + quad) ^ xa) * 8];
#pragma unroll
      for (int mt = 0; mt < 4; ++mt)
#pragma unroll
        for (int nt = 0; nt < 4; ++nt)
          acc[mt][nt] = __builtin_amdgcn_mfma_f32_16x16x32_f16(
              af[mt], bf[nt], acc[mt][nt], 0, 0, 0);
    }
  }
  __syncthreads();  // last fragment reads done before epilogue reuses smem

  OutT* Ob = Out + (size_t)z * M * N;
  if constexpr (sizeof(OutT) == 2) {
    // ---- f16 out: single-pass 128x128 transpose tile, stride 136 ----
    _Float16* T = (_Float16*)smem;
#pragma unroll
    for (int mt = 0; mt < 4; ++mt) {
      const int m0 = bm + wm * 64 + mt * 16 + quad * 4;
      float bm4[4];
#pragma unroll
      for (int i = 0; i < 4; ++i) bm4[i] = BIAS_ON_M ? bias[m0 + i] : 0.f;
#pragma unroll
      for (int nt = 0; nt < 4; ++nt) {
        const int nl = wn * 64 + nt * 16 + lx;
        const float bn1 = BIAS_ON_M ? 0.f : bias[bn + nl];
        f16x4 o = {(_Float16)(acc[mt][nt][0] + (BIAS_ON_M ? bm4[0] : bn1)),
                   (_Float16)(acc[mt][nt][1] + (BIAS_ON_M ? bm4[1] : bn1)),
                   (_Float16)(acc[mt][nt][2] + (BIAS_ON_M ? bm4[2] : bn1)),
                   (_Float16)(acc[mt][nt][3] + (BIAS_ON_M ? bm4[3] : bn1))};
        *(f16x4*)&T[nl * 136 + wm * 64 + mt * 16 + quad * 4] = o;
      }
    }
    __syncthreads();
#pragma unroll
    for (int j = 0; j < 8; ++j) {
      const int r = j * 16 + (tid >> 4), slot = tid & 15;
      f16x8 vv = *(const f16x8*)&T[r * 136 + slot * 8];
      *(f16x8*)((_Float16*)Ob + (size_t)(bn + r) * M + bm + slot * 8) = vv;
    }
  } else {
    // ---- f32 out: two half-passes (64 n-rows each), stride 136 ----
    float* T32 = (float*)smem;
#pragma unroll
    for (int p = 0; p < 2; ++p) {
      __syncthreads();
      if (wn == p) {
#pragma unroll
        for (int mt = 0; mt < 4; ++mt) {
          const int m0 = bm + wm * 64 + mt * 16 + quad * 4;
          float bm4[4];
#pragma unroll
          for (int i = 0; i < 4; ++i) bm4[i] = BIAS_ON_M ? bias[m0 + i] : 0.f;
#pragma unroll
          for (int nt = 0; nt < 4; ++nt) {
            const int nl = nt * 16 + lx;
            const float bn1 = BIAS_ON_M ? 0.f : bias[bn + p * 64 + nl];
            float4 o = {acc[mt][nt][0] + (BIAS_ON_M ? bm4[0] : bn1),
                        acc[mt][nt][1] + (BIAS_ON_M ? bm4[1] : bn1),
                        acc[mt][nt][2] + (BIAS_ON_M ? bm4[2] : bn1),
                        acc[mt][nt][3] + (BIAS_ON_M ? bm4[3] : bn1)};
            *(float4*)&T32[nl * 136 + wm * 64 + mt * 16 + quad * 4] = o;
          }
        }
      }
      __syncthreads();
#pragma unroll
      for (int j = 0; j < 8; ++j) {
        const int r = j * 8 + (tid >> 5), slot = tid & 31;
        float4 vv = *(const float4*)&T32[r * 136 + slot * 4];
        *(float4*)((float*)Ob + (size_t)(bn + p * 64 + r) * M + bm + slot * 4) =
            vv;
      }
    }
  }
}

// ------------------------- fp16 MFMA flash attention ------------------------
// qkvT layout: [b][l][o], o = h*192 + {0..63 q, 64..127 k, 128..191 v}.
// Block = (b,h) x 128 t-tile, 4 waves; wave w owns t-cols w*32+{0..15,16..31}.
// Fixed-max softmax (verified R4/R5): p = exp2(S'), l lane-local, epilogue
// reduce. Grid (bh=128, t=8) pins a head's t-tiles to one XCD (K/V L2-hit).
// ONE barrier per s-tile: K async-dbuf (kb0/kb1, XOR involution), V reg-dbuf
// (vb0/vb1). body(i): dsWriteV(i)->vb[i&1]; barrier; prefetch(i+1);
// QK(kb[i&1]); softmax; PV(vb[i&1]). Barrier proves iter i-1 fully retired
// in all waves -> prefetch targets have no readers; implicit vmcnt(0)
// drains 1-iter-old loads at zero cost.
#define LV 70
#define QSCALE 0.18033688011112042f  // 0.125 * log2(e)

__global__ __launch_bounds__(256) void attn_mfma(
    const _Float16* __restrict__ qkvT, _Float16* __restrict__ aT) {
  __shared__ __align__(16) _Float16 kb0[64 * 64];  // 8 KB [s][ch] swizzled
  __shared__ __align__(16) _Float16 kb1[64 * 64];  // 8 KB
  __shared__ __align__(16) _Float16 vb0[64 * LV];  // [ch][s] 8.75 KB
  __shared__ __align__(16) _Float16 vb1[64 * LV];  // [ch][s] 8.75 KB

  const int tid = threadIdx.x;
  const int w = tid >> 6, lane = tid & 63;
  const int lx = lane & 15, quad = lane >> 4;
  const int bh = blockIdx.x, b = bh >> 3, h = bh & 7;
  const int t0 = blockIdx.y * 128;
  const _Float16* qb = qkvT + (size_t)b * 1024 * 1536 + h * 192;

  // ---- Q B-frags from global (once), scale 0.125*log2e folded in ----
  f16x8 qf[2][2];
#pragma unroll
  for (int g = 0; g < 2; ++g) {
    const _Float16* qrow = qb + (size_t)(t0 + w * 32 + g * 16 + lx) * 1536;
    qf[g][0] = *(const f16x8*)(qrow + quad * 8);
    qf[g][1] = *(const f16x8*)(qrow + 32 + quad * 8);
#pragma unroll
    for (int j = 0; j < 8; ++j) {
      qf[g][0][j] = qf[g][0][j] * (_Float16)QSCALE;
      qf[g][1][j] = qf[g][1][j] * (_Float16)QSCALE;
    }
  }

  // ---- K async staging geometry (rule-#21 XOR involution) ----
  const _Float16* kgs = qb + (size_t)(w * 16 + (lane >> 3)) * 1536 + 64 +
                        (((lane & 7) ^ ((lane >> 3) & 7)) * 8);
  _Float16* const kld0 = &kb0[(w * 16) * 64];
  _Float16* const kld1 = &kb1[(w * 16) * 64];

  // ---- V staging geometry (reg path, transpose scatter) ----
  const int vs2 = (tid >> 3) * 2, vc8 = (tid & 7) * 8;  // s-pair, ch8
  const _Float16* vgp = qb + (size_t)vs2 * 1536 + 128 + vc8;

  // ---- prologue: asyncK tile0 -> kb0; V tile0 -> regs ----
  async_cp16(kgs, kld0);
  async_cp16(kgs + (size_t)8 * 1536, kld0 + 8 * 64);
  f16x8 vp0 = *(const f16x8*)vgp;
  f16x8 vp1 = *(const f16x8*)(vgp + 1536);

  float l_r[2] = {0.f, 0.f};
  f32x4 oacc[2][4];  // [g][mt]: D[m=ch: mt*16+quad*4+i][n=t: w*32+g*16+lx]
#pragma unroll
  for (int g = 0; g < 2; ++g)
#pragma unroll
    for (int mt = 0; mt < 4; ++mt) oacc[g][mt] = (f32x4){0.f, 0.f, 0.f, 0.f};

  const int xa = lx & 7;

  auto body = [&](int s0, const _Float16* kcur, _Float16* kldn,
                  _Float16* vcur) {
    // ---- V(s0) regs -> vcur (transposed, s-pairs packed b32) ----
#pragma unroll
    for (int i = 0; i < 8; ++i) {
      union { _Float16 hh[2]; unsigned u; } p;
      p.hh[0] = vp0[i];
      p.hh[1] = vp1[i];
      *(unsigned*)&vcur[(vc8 + i) * LV + vs2] = p.u;
    }
    __syncthreads();  // vcur visible; drains asyncK(s0) (1 iter old, free)

    // ---- prefetch tile s0+64: asyncK -> kldn, V -> regs ----
    if (s0 + 64 < 1024) {
      async_cp16(kgs + (size_t)(s0 + 64) * 1536, kldn);
      async_cp16(kgs + (size_t)(s0 + 72) * 1536, kldn + 8 * 64);
      const _Float16* vg2 = vgp + (size_t)(s0 + 64) * 1536;
      vp0 = *(const f16x8*)vg2;
      vp1 = *(const f16x8*)(vg2 + 1536);
    }

    // ---- S^T[s][t] both groups; K-frags read once per sb ----
    f32x4 sf[2][4];
#pragma unroll
    for (int sb = 0; sb < 4; ++sb) {
      f16x8 k0 = *(const f16x8*)&kcur[(sb * 16 + lx) * 64 + ((quad ^ xa) * 8)];
      f16x8 k1 =
          *(const f16x8*)&kcur[(sb * 16 + lx) * 64 + (((4 + quad) ^ xa) * 8)];
#pragma unroll
      for (int g = 0; g < 2; ++g) {
        f32x4 z = {0.f, 0.f, 0.f, 0.f};
        z = __builtin_amdgcn_mfma_f32_16x16x32_f16(k0, qf[g][0], z, 0, 0, 0);
        sf[g][sb] =
            __builtin_amdgcn_mfma_f32_16x16x32_f16(k1, qf[g][1], z, 0, 0, 0);
      }
    }

    // ---- softmax-lite: p = exp2(S'), packed cvt, lane-local l ----
    f16x4 pf[2][4];
#pragma unroll
    for (int g = 0; g < 2; ++g) {
      float sum = 0.f;
#pragma unroll
      for (int sb = 0; sb < 4; ++sb) {
        float p0 = __builtin_amdgcn_exp2f(sf[g][sb][0]);
        float p1 = __builtin_amdgcn_exp2f(sf[g][sb][1]);
        float p2 = __builtin_amdgcn_exp2f(sf[g][sb][2]);
        float p3 = __builtin_amdgcn_exp2f(sf[g][sb][3]);
        sum += (p0 + p1) + (p2 + p3);
        union { fp16x2 h2[2]; f16x4 h4; } pk;
        pk.h2[0] = __builtin_amdgcn_cvt_pkrtz(p0, p1);
        pk.h2[1] = __builtin_amdgcn_cvt_pkrtz(p2, p3);
        pf[g][sb] = pk.h4;
      }
      l_r[g] += sum;
    }

    // ---- PV: V-frag read once serves both groups ----
#pragma unroll
    for (int kb = 0; kb < 4; ++kb)
#pragma unroll
      for (int mt = 0; mt < 4; ++mt) {
        f16x4 vf =
            *(const f16x4*)&vcur[(mt * 16 + lx) * LV + kb * 16 + quad * 4];
        oacc[0][mt] = MFMA_K16(vf, pf[0][kb], oacc[0][mt]);
        oacc[1][mt] = MFMA_K16(vf, pf[1][kb], oacc[1][mt]);
      }
  };

  for (int s0 = 0; s0 < 1024; s0 += 128) {
    body(s0, kb0, kld1, vb0);        // even tile: read kb0, prefetch->kb1
    body(s0 + 64, kb1, kld0, vb1);   // odd tile:  read kb1, prefetch->kb0
  }

  // ---- epilogue: reduce l across quads once; aT[b][t][h*64+ch] = O/l ----
#pragma unroll
  for (int g = 0; g < 2; ++g) {
    float l = l_r[g];
    l += __shfl_xor(l, 16);
    l += __shfl_xor(l, 32);
    const float linv = 1.f / l;
    _Float16* ob =
        aT + ((size_t)b * 1024 + t0 + w * 32 + g * 16 + lx) * 512 + h * 64;
#pragma unroll
    for (int mt = 0; mt < 4; ++mt) {
      f16x4 o = {(_Float16)(oacc[g][mt][0] * linv),
                 (_Float16)(oacc[g][mt][1] * linv),
                 (_Float16)(oacc[g][mt][2] * linv),
                 (_Float16)(oacc[g][mt][3] * linv)};
      *(f16x4*)&ob[mt * 16 + quad * 4] = o;
    }
  }
}

// ---------------------------------------------------------------------------
extern "C" void kernel_launch(void* const* d_in, const int* in_sizes, int n_in,
                              void* d_out, int out_size, void* d_ws,
                              size_t ws_size, hipStream_t stream) {
  const float* x = (const float*)d_in[0];
  const float* norm_w = (const float*)d_in[1];
  const float* norm_b = (const float*)d_in[2];
  const float* w_qkv = (const float*)d_in[3];
  const float* b_qkv = (const float*)d_in[4];
  const float* w_proj = (const float*)d_in[5];
  const float* b_proj = (const float*)d_in[6];
  float* out = (float*)d_out;

  _Float16* hT = (_Float16*)d_ws;
  _Float16* qkvT = hT + (size_t)16 * 1024 * 512;
  _Float16* wq = qkvT + (size_t)16 * 1024 * 1536;
  _Float16* wp = wq + (size_t)1536 * 512;
  _Float16* aT = hT;

  cvt_weights<<<1024, 256, 0, stream>>>(w_qkv, w_proj, wq, wp);
  gn_kernel<<<512, 256, 0, stream>>>(x, norm_w, norm_b, hT);
  gemm_tn<_Float16, true><<<dim3(8, 12, 16), 256, 0, stream>>>(
      wq, hT, b_qkv, qkvT, 1536, 1024, 512, 0L, 524288L);
  attn_mfma<<<dim3(128, 8), 256, 0, stream>>>(qkvT, aT);
  gemm_tn<float, false><<<dim3(4, 8, 16), 256, 0, stream>>>(
      aT, wp, b_proj, out, 1024, 512, 512, 524288L, 0L);
}

// Round 11
// 203.892 us; speedup vs baseline: 1.3585x; 1.3585x over previous
//
#include <hip/hip_runtime.h>
#include <math.h>

// ---------------------------------------------------------------------------
// AttentionBlock: GroupNorm(32) -> QKV proj -> MHA(8 heads) -> out proj
// B=16, C=512, L=1024, group=16ch, head ch=64.
// Round 17: REVERT attn to R8/R15 two-barrier schedule (one-barrier dbuf
//           regressed 58.6->140.6us: vmcnt(0) drain at top-of-body with only
//           4 blocks/CU of TLP; second structural-restructure failure after
//           R3 -> barrier skeleton is frozen from here).
//           NEW: gn grid remap id = g*16+b (was b*32+g). hT 64B lines are
//           co-written by group pairs; old map put the pair on different
//           XCDs (XCD = g%8) -> partial-line writebacks from two L2s (~2x
//           write amplification). New map: XCD = b%8, all groups of a batch
//           share an XCD -> lines merge in L2 before writeback.
// ---------------------------------------------------------------------------

typedef _Float16 f16x8 __attribute__((ext_vector_type(8)));
typedef _Float16 f16x4 __attribute__((ext_vector_type(4)));
typedef float f32x4 __attribute__((ext_vector_type(4)));

// NOTE: legacy K=16 fp16 MFMA builtin has NO underscore before f16.
#define MFMA_K16(A, B, C) __builtin_amdgcn_mfma_f32_16x16x16f16(A, B, C, 0, 0, 0)

// async 16B/lane global->LDS copy. LDS dest is WAVE-UNIFORM base; HW places
// lane i at base + i*16. Global src is per-lane.
__device__ __forceinline__ void async_cp16(const void* g, void* l) {
  __builtin_amdgcn_global_load_lds(
      (const __attribute__((address_space(1))) void*)g,
      (__attribute__((address_space(3))) void*)l, 16, 0, 0);
}

// ------------------------- weight fp32 -> fp16 (both, one launch) -----------
__global__ __launch_bounds__(256) void cvt_weights(
    const float* __restrict__ wq, const float* __restrict__ wp,
    _Float16* __restrict__ dq, _Float16* __restrict__ dp) {
  int i = blockIdx.x * 256 + threadIdx.x;
  if (i < 196608) {
    float4 v = ((const float4*)wq)[i];
    f16x4 o = {(_Float16)v.x, (_Float16)v.y, (_Float16)v.z, (_Float16)v.w};
    *(f16x4*)&dq[(size_t)i * 4] = o;
  } else {
    int j = i - 196608;  // < 65536 by grid sizing
    float4 v = ((const float4*)wp)[j];
    f16x4 o = {(_Float16)v.x, (_Float16)v.y, (_Float16)v.z, (_Float16)v.w};
    *(f16x4*)&dp[(size_t)j * 4] = o;
  }
}

// ------------------------- GroupNorm (writes hT [b][l][c] fp16) -------------
// Grid: blockIdx.x = g*16 + b  (XCD = b%8: all groups of a batch share XCD,
// so the 64B hT lines co-written by group pairs merge in one L2).
__global__ __launch_bounds__(256) void gn_kernel(
    const float* __restrict__ x, const float* __restrict__ gw,
    const float* __restrict__ gb, _Float16* __restrict__ hT) {
  const int b = blockIdx.x & 15;
  const int g = blockIdx.x >> 4;
  const size_t base = ((size_t)(b * 512 + g * 16)) * 1024;
  const float4* xp = (const float4*)(x + base);
  const int tid = threadIdx.x;

  float4 vals[16];
  float s = 0.f, sq = 0.f;
#pragma unroll
  for (int r = 0; r < 16; ++r) {
    float4 v = xp[tid + 256 * r];
    vals[r] = v;
    s += v.x + v.y + v.z + v.w;
    sq += v.x * v.x + v.y * v.y + v.z * v.z + v.w * v.w;
  }
  __shared__ float rs[256];
  __shared__ float rq[256];
  rs[tid] = s;
  rq[tid] = sq;
  __syncthreads();
  for (int off = 128; off > 0; off >>= 1) {
    if (tid < off) {
      rs[tid] += rs[tid + off];
      rq[tid] += rq[tid + off];
    }
    __syncthreads();
  }
  const float mean = rs[0] * (1.f / 16384.f);
  const float var = rq[0] * (1.f / 16384.f) - mean * mean;
  const float rinv = rsqrtf(var + 1e-5f);
#pragma unroll
  for (int r = 0; r < 16; ++r) {
    const int c = g * 16 + r;
    const float wc = gw[c] * rinv;
    const float bc = gb[c] - mean * wc;
    vals[r].x = vals[r].x * wc + bc;
    vals[r].y = vals[r].y * wc + bc;
    vals[r].z = vals[r].z * wc + bc;
    vals[r].w = vals[r].w * wc + bc;
  }
  _Float16* hb = hT + ((size_t)b * 1024 + tid * 4) * 512 + g * 16;
#pragma unroll
  for (int li = 0; li < 4; ++li) {
    f16x8 o0, o1;
#pragma unroll
    for (int r = 0; r < 8; ++r) {
      float v0 = li == 0 ? vals[r].x : li == 1 ? vals[r].y
                 : li == 2 ? vals[r].z : vals[r].w;
      float v1 = li == 0 ? vals[8 + r].x : li == 1 ? vals[8 + r].y
                 : li == 2 ? vals[8 + r].z : vals[8 + r].w;
      o0[r] = (_Float16)v0;
      o1[r] = (_Float16)v1;
    }
    *(f16x8*)(hb + (size_t)li * 512) = o0;
    *(f16x8*)(hb + (size_t)li * 512 + 8) = o1;
  }
}

// ------------------------- fp16 MFMA GEMM, BK=64 single buffer --------------
// C[m][n] = sum_k A[m][k]*B[n][k] (+bias), stored TRANSPOSED: Out[n][m].
// 128x128 tile, BK=64, 8 K-steps (K=512). LDS rows are 128B linear (async
// copy needs contiguous dest); bank uniformity via XOR source swizzle:
// LDS phys 16B-chunk p of row r holds logical chunk p ^ (r&7); fragment
// reads apply the same XOR.
// Epilogue: C-frags (+bias) -> LDS [n][m] tile -> coalesced row stores.
template <typename OutT, bool BIAS_ON_M>
__global__ __launch_bounds__(256) void gemm_tn(
    const _Float16* __restrict__ A, const _Float16* __restrict__ B,
    const float* __restrict__ bias, OutT* __restrict__ Out,
    int M, int N, int K, long sA, long sB) {
  // smem: As(16K) Bs(16K) = 32K | epilogue T (34.8K)
  __shared__ __align__(16) char smem[34816];
  _Float16* As = (_Float16*)smem;
  _Float16* Bs = As + 128 * 64;
  const int tid = threadIdx.x;
  const int w = tid >> 6, lane = tid & 63;
  const int lx = lane & 15, quad = lane >> 4;
  const int wm = w >> 1, wn = w & 1;
  const int bn = blockIdx.x * 128, bm = blockIdx.y * 128;
  const int z = blockIdx.z;

  // staging geometry: row = w*32 + j*8 + (lane>>3); phys chunk = lane&7;
  // global logical chunk = (lane&7) ^ ((lane>>3)&7)  [row&7 == (lane>>3)&7]
  const int srow = w * 32 + (lane >> 3);
  const int scol = (((lane & 7) ^ ((lane >> 3) & 7)) * 8);
  const _Float16* Ag = A + (size_t)z * sA + (size_t)(bm + srow) * K + scol;
  const _Float16* Bg = B + (size_t)z * sB + (size_t)(bn + srow) * K + scol;

  f32x4 acc[4][4];
#pragma unroll
  for (int i = 0; i < 4; ++i)
#pragma unroll
    for (int j = 0; j < 4; ++j) acc[i][j] = (f32x4){0.f, 0.f, 0.f, 0.f};

  const int xa = lx & 7;  // row&7 for this lane's fragment rows

  for (int k0 = 0; k0 < K; k0 += 64) {
    __syncthreads();  // prior step's fragment reads complete
#pragma unroll
    for (int j = 0; j < 4; ++j) {
      async_cp16(Ag + (size_t)j * 8 * K + k0, &As[(w * 32 + j * 8) * 64]);
      async_cp16(Bg + (size_t)j * 8 * K + k0, &Bs[(w * 32 + j * 8) * 64]);
    }
    __syncthreads();  // implicit vmcnt(0): buffer ready
#pragma unroll
    for (int h = 0; h < 2; ++h) {
      f16x8 af[4], bf[4];
#pragma unroll
      for (int mt = 0; mt < 4; ++mt)
        af[mt] = *(const f16x8*)&As[(wm * 64 + mt * 16 + lx) * 64 +
                                    ((h * 4 + quad) ^ xa) * 8];
#pragma unroll
      for (int nt = 0; nt < 4; ++nt)
        bf[nt] = *(const f16x8*)&Bs[(wn * 64 + nt * 16 + lx) * 64 +
                                    ((h * 4 + quad) ^ xa) * 8];
#pragma unroll
      for (int mt = 0; mt < 4; ++mt)
#pragma unroll
        for (int nt = 0; nt < 4; ++nt)
          acc[mt][nt] = __builtin_amdgcn_mfma_f32_16x16x32_f16(
              af[mt], bf[nt], acc[mt][nt], 0, 0, 0);
    }
  }
  __syncthreads();  // last fragment reads done before epilogue reuses smem

  OutT* Ob = Out + (size_t)z * M * N;
  if constexpr (sizeof(OutT) == 2) {
    // ---- f16 out: single-pass 128x128 transpose tile, stride 136 ----
    _Float16* T = (_Float16*)smem;
#pragma unroll
    for (int mt = 0; mt < 4; ++mt) {
      const int m0 = bm + wm * 64 + mt * 16 + quad * 4;
      float bm4[4];
#pragma unroll
      for (int i = 0; i < 4; ++i) bm4[i] = BIAS_ON_M ? bias[m0 + i] : 0.f;
#pragma unroll
      for (int nt = 0; nt < 4; ++nt) {
        const int nl = wn * 64 + nt * 16 + lx;
        const float bn1 = BIAS_ON_M ? 0.f : bias[bn + nl];
        f16x4 o = {(_Float16)(acc[mt][nt][0] + (BIAS_ON_M ? bm4[0] : bn1)),
                   (_Float16)(acc[mt][nt][1] + (BIAS_ON_M ? bm4[1] : bn1)),
                   (_Float16)(acc[mt][nt][2] + (BIAS_ON_M ? bm4[2] : bn1)),
                   (_Float16)(acc[mt][nt][3] + (BIAS_ON_M ? bm4[3] : bn1))};
        *(f16x4*)&T[nl * 136 + wm * 64 + mt * 16 + quad * 4] = o;
      }
    }
    __syncthreads();
#pragma unroll
    for (int j = 0; j < 8; ++j) {
      const int r = j * 16 + (tid >> 4), slot = tid & 15;
      f16x8 vv = *(const f16x8*)&T[r * 136 + slot * 8];
      *(f16x8*)((_Float16*)Ob + (size_t)(bn + r) * M + bm + slot * 8) = vv;
    }
  } else {
    // ---- f32 out: two half-passes (64 n-rows each), stride 136 ----
    float* T32 = (float*)smem;
#pragma unroll
    for (int p = 0; p < 2; ++p) {
      __syncthreads();
      if (wn == p) {
#pragma unroll
        for (int mt = 0; mt < 4; ++mt) {
          const int m0 = bm + wm * 64 + mt * 16 + quad * 4;
          float bm4[4];
#pragma unroll
          for (int i = 0; i < 4; ++i) bm4[i] = BIAS_ON_M ? bias[m0 + i] : 0.f;
#pragma unroll
          for (int nt = 0; nt < 4; ++nt) {
            const int nl = nt * 16 + lx;
            const float bn1 = BIAS_ON_M ? 0.f : bias[bn + p * 64 + nl];
            float4 o = {acc[mt][nt][0] + (BIAS_ON_M ? bm4[0] : bn1),
                        acc[mt][nt][1] + (BIAS_ON_M ? bm4[1] : bn1),
                        acc[mt][nt][2] + (BIAS_ON_M ? bm4[2] : bn1),
                        acc[mt][nt][3] + (BIAS_ON_M ? bm4[3] : bn1)};
            *(float4*)&T32[nl * 136 + wm * 64 + mt * 16 + quad * 4] = o;
          }
        }
      }
      __syncthreads();
#pragma unroll
      for (int j = 0; j < 8; ++j) {
        const int r = j * 8 + (tid >> 5), slot = tid & 31;
        float4 vv = *(const float4*)&T32[r * 136 + slot * 4];
        *(float4*)((float*)Ob + (size_t)(bn + p * 64 + r) * M + bm + slot * 4) =
            vv;
      }
    }
  }
}

// ------------------------- fp16 MFMA flash attention ------------------------
// qkvT layout: [b][l][o], o = h*192 + {0..63 q, 64..127 k, 128..191 v}.
// Block = (b,h) x 128 t-tile, 4 waves; wave w owns t-cols w*32+{0..15,16..31}.
// Fixed-max softmax (verified R4/R5): p = exp2(S'), l lane-local, epilogue
// reduce. Grid (bh=128, t=8) pins a head's t-tiles to one XCD (K/V L2-hit).
// K staging: global_load_lds into double-buffered linear [64][64] tiles,
// XOR involution (src chunk^(row&7) / read chunk^(lx&7)), 2 issues/wave/tile.
// asyncK(cur) is drained by the barrier after V ds-writes (a full tile after
// issue -> latency hidden). V reg-staged + packed b32 scatter (transpose).
// Two barriers/tile: FROZEN (one-barrier variants regressed 2.4x, R10/R3).
#define LV 70
#define QSCALE 0.18033688011112042f  // 0.125 * log2(e)

__global__ __launch_bounds__(256) void attn_mfma(
    const _Float16* __restrict__ qkvT, _Float16* __restrict__ aT) {
  __shared__ __align__(16) _Float16 kb0[64 * 64];  // 8 KB, [s][ch] swizzled
  __shared__ __align__(16) _Float16 kb1[64 * 64];  // 8 KB
  __shared__ __align__(16) _Float16 vs[64 * LV];   // [ch][s]  8.75 KB

  const int tid = threadIdx.x;
  const int w = tid >> 6, lane = tid & 63;
  const int lx = lane & 15, quad = lane >> 4;
  const int bh = blockIdx.x, b = bh >> 3, h = bh & 7;
  const int t0 = blockIdx.y * 128;
  const _Float16* qb = qkvT + (size_t)b * 1024 * 1536 + h * 192;

  // ---- Q B-frags from global (once), scale 0.125*log2e folded in ----
  f16x8 qf[2][2];
#pragma unroll
  for (int g = 0; g < 2; ++g) {
    const _Float16* qrow = qb + (size_t)(t0 + w * 32 + g * 16 + lx) * 1536;
    qf[g][0] = *(const f16x8*)(qrow + quad * 8);
    qf[g][1] = *(const f16x8*)(qrow + 32 + quad * 8);
#pragma unroll
    for (int j = 0; j < 8; ++j) {
      qf[g][0][j] = qf[g][0][j] * (_Float16)QSCALE;
      qf[g][1][j] = qf[g][1][j] * (_Float16)QSCALE;
    }
  }

  // ---- K async staging geometry: wave w covers rows w*16..w*16+15 in two
  // 8-row (1KB) calls; lane i -> row +(i>>3), phys chunk i&7, global logical
  // chunk (i&7)^((i>>3)&7). LDS base wave-uniform. ----
  const _Float16* kgs = qb + (size_t)(w * 16 + (lane >> 3)) * 1536 + 64 +
                        (((lane & 7) ^ ((lane >> 3) & 7)) * 8);
  _Float16* const kld0 = &kb0[(w * 16) * 64];
  _Float16* const kld1 = &kb1[(w * 16) * 64];

  // ---- V staging geometry (reg path, transpose scatter) ----
  const int vs2 = (tid >> 3) * 2, vc8 = (tid & 7) * 8;  // s-pair, ch8
  const _Float16* vgp = qb + (size_t)vs2 * 1536 + 128 + vc8;

  // ---- prologue: asyncK tile0 -> kb0; V tile0 -> regs ----
  async_cp16(kgs, kld0);
  async_cp16(kgs + (size_t)8 * 1536, kld0 + 8 * 64);
  f16x8 vp0 = *(const f16x8*)vgp;
  f16x8 vp1 = *(const f16x8*)(vgp + 1536);

  float l_r[2] = {0.f, 0.f};
  f32x4 oacc[2][4];  // [g][mt]: D[m=ch: mt*16+quad*4+i][n=t: w*32+g*16+lx]
#pragma unroll
  for (int g = 0; g < 2; ++g)
#pragma unroll
    for (int mt = 0; mt < 4; ++mt) oacc[g][mt] = (f32x4){0.f, 0.f, 0.f, 0.f};

  const int xa = lx & 7;

  auto tile = [&](int s0, const _Float16* kcur, _Float16* kldn) {
    __syncthreads();  // sync1: prior tile's vs reads complete
    // ---- V regs -> vs (transposed, s-pairs packed b32) ----
#pragma unroll
    for (int i = 0; i < 8; ++i) {
      union { _Float16 hh[2]; unsigned u; } p;
      p.hh[0] = vp0[i];
      p.hh[1] = vp1[i];
      *(unsigned*)&vs[(vc8 + i) * LV + vs2] = p.u;
    }
    __syncthreads();  // sync2: vs visible; implicit vmcnt(0) lands asyncK(cur)

    // ---- issue next tile's asyncK + V reg loads (hide under compute) ----
    if (s0 + 64 < 1024) {
      async_cp16(kgs + (size_t)(s0 + 64) * 1536, kldn);
      async_cp16(kgs + (size_t)(s0 + 72) * 1536, kldn + 8 * 64);
      const _Float16* vg2 = vgp + (size_t)(s0 + 64) * 1536;
      vp0 = *(const f16x8*)vg2;
      vp1 = *(const f16x8*)(vg2 + 1536);
    }

    // ---- S^T[s][t] both groups; K-frags read once per sb ----
    f32x4 sf[2][4];
#pragma unroll
    for (int sb = 0; sb < 4; ++sb) {
      f16x8 k0 = *(const f16x8*)&kcur[(sb * 16 + lx) * 64 + ((quad ^ xa) * 8)];
      f16x8 k1 =
          *(const f16x8*)&kcur[(sb * 16 + lx) * 64 + (((4 + quad) ^ xa) * 8)];
#pragma unroll
      for (int g = 0; g < 2; ++g) {
        f32x4 z = {0.f, 0.f, 0.f, 0.f};
        z = __builtin_amdgcn_mfma_f32_16x16x32_f16(k0, qf[g][0], z, 0, 0, 0);
        sf[g][sb] =
            __builtin_amdgcn_mfma_f32_16x16x32_f16(k1, qf[g][1], z, 0, 0, 0);
      }
    }

    // ---- softmax-lite: p = exp2(S'), lane-local l accumulation ----
    f16x4 pf[2][4];
#pragma unroll
    for (int g = 0; g < 2; ++g) {
      float sum = 0.f;
#pragma unroll
      for (int sb = 0; sb < 4; ++sb) {
        float p0 = __builtin_amdgcn_exp2f(sf[g][sb][0]);
        float p1 = __builtin_amdgcn_exp2f(sf[g][sb][1]);
        float p2 = __builtin_amdgcn_exp2f(sf[g][sb][2]);
        float p3 = __builtin_amdgcn_exp2f(sf[g][sb][3]);
        sum += (p0 + p1) + (p2 + p3);
        pf[g][sb] =
            (f16x4){(_Float16)p0, (_Float16)p1, (_Float16)p2, (_Float16)p3};
      }
      l_r[g] += sum;
    }

    // ---- PV: V-frag read once serves both groups ----
#pragma unroll
    for (int kb = 0; kb < 4; ++kb)
#pragma unroll
      for (int mt = 0; mt < 4; ++mt) {
        f16x4 vf = *(const f16x4*)&vs[(mt * 16 + lx) * LV + kb * 16 + quad * 4];
        oacc[0][mt] = MFMA_K16(vf, pf[0][kb], oacc[0][mt]);
        oacc[1][mt] = MFMA_K16(vf, pf[1][kb], oacc[1][mt]);
      }
  };

  for (int s0 = 0; s0 < 1024; s0 += 128) {
    tile(s0, kb0, kld1);       // compute kb0, stage next into kb1
    tile(s0 + 64, kb1, kld0);  // compute kb1, stage next into kb0
  }

  // ---- epilogue: reduce l across quads once; aT[b][t][h*64+ch] = O/l ----
#pragma unroll
  for (int g = 0; g < 2; ++g) {
    float l = l_r[g];
    l += __shfl_xor(l, 16);
    l += __shfl_xor(l, 32);
    const float linv = 1.f / l;
    _Float16* ob =
        aT + ((size_t)b * 1024 + t0 + w * 32 + g * 16 + lx) * 512 + h * 64;
#pragma unroll
    for (int mt = 0; mt < 4; ++mt) {
      f16x4 o = {(_Float16)(oacc[g][mt][0] * linv),
                 (_Float16)(oacc[g][mt][1] * linv),
                 (_Float16)(oacc[g][mt][2] * linv),
                 (_Float16)(oacc[g][mt][3] * linv)};
      *(f16x4*)&ob[mt * 16 + quad * 4] = o;
    }
  }
}

// ---------------------------------------------------------------------------
extern "C" void kernel_launch(void* const* d_in, const int* in_sizes, int n_in,
                              void* d_out, int out_size, void* d_ws,
                              size_t ws_size, hipStream_t stream) {
  const float* x = (const float*)d_in[0];
  const float* norm_w = (const float*)d_in[1];
  const float* norm_b = (const float*)d_in[2];
  const float* w_qkv = (const float*)d_in[3];
  const float* b_qkv = (const float*)d_in[4];
  const float* w_proj = (const float*)d_in[5];
  const float* b_proj = (const float*)d_in[6];
  float* out = (float*)d_out;

  _Float16* hT = (_Float16*)d_ws;
  _Float16* qkvT = hT + (size_t)16 * 1024 * 512;
  _Float16* wq = qkvT + (size_t)16 * 1024 * 1536;
  _Float16* wp = wq + (size_t)1536 * 512;
  _Float16* aT = hT;

  cvt_weights<<<1024, 256, 0, stream>>>(w_qkv, w_proj, wq, wp);
  gn_kernel<<<512, 256, 0, stream>>>(x, norm_w, norm_b, hT);
  gemm_tn<_Float16, true><<<dim3(8, 12, 16), 256, 0, stream>>>(
      wq, hT, b_qkv, qkvT, 1536, 1024, 512, 0L, 524288L);
  attn_mfma<<<dim3(128, 8), 256, 0, stream>>>(qkvT, aT);
  gemm_tn<float, false><<<dim3(4, 8, 16), 256, 0, stream>>>(
      aT, wp, b_proj, out, 1024, 512, 512, 524288L, 0L);
}

// Round 12
// 199.598 us; speedup vs baseline: 1.3877x; 1.0215x over previous
//
#include <hip/hip_runtime.h>
#include <math.h>

// ---------------------------------------------------------------------------
// AttentionBlock: GroupNorm(32) -> QKV proj -> MHA(8 heads) -> out proj
// B=16, C=512, L=1024, group=16ch, head ch=64.
// Round 18: (a) attn P-conversion via v_cvt_pkrtz (32 scalar cvt -> 16
//           packed) on the proven R11 two-barrier structure;
//           (b) cvt_weights fused into gn launch (blocks 0-511 = gn with
//           XCD remap, 512-1535 = weight convert) -> one fewer launch.
//           Everything else frozen (R11-verified).
// ---------------------------------------------------------------------------

typedef _Float16 f16x8 __attribute__((ext_vector_type(8)));
typedef _Float16 f16x4 __attribute__((ext_vector_type(4)));
typedef __fp16 fp16x2 __attribute__((ext_vector_type(2)));  // cvt_pkrtz type
typedef float f32x4 __attribute__((ext_vector_type(4)));

// NOTE: legacy K=16 fp16 MFMA builtin has NO underscore before f16.
#define MFMA_K16(A, B, C) __builtin_amdgcn_mfma_f32_16x16x16f16(A, B, C, 0, 0, 0)

// async 16B/lane global->LDS copy. LDS dest is WAVE-UNIFORM base; HW places
// lane i at base + i*16. Global src is per-lane.
__device__ __forceinline__ void async_cp16(const void* g, void* l) {
  __builtin_amdgcn_global_load_lds(
      (const __attribute__((address_space(1))) void*)g,
      (__attribute__((address_space(3))) void*)l, 16, 0, 0);
}

// --------------- GroupNorm (blocks 0-511) + weight cvt (512-1535) -----------
// gn grid: id = g*16 + b (XCD = b%8: all groups of a batch share an XCD so
// co-written 64B hT lines merge in one L2 before writeback).
__global__ __launch_bounds__(256) void gn_cvt(
    const float* __restrict__ x, const float* __restrict__ gw,
    const float* __restrict__ gb, _Float16* __restrict__ hT,
    const float* __restrict__ wq, const float* __restrict__ wp,
    _Float16* __restrict__ dq, _Float16* __restrict__ dp) {
  const int tid = threadIdx.x;
  if (blockIdx.x >= 512) {
    // ---- weight fp32 -> fp16 ----
    int i = (blockIdx.x - 512) * 256 + tid;
    if (i < 196608) {
      float4 v = ((const float4*)wq)[i];
      f16x4 o = {(_Float16)v.x, (_Float16)v.y, (_Float16)v.z, (_Float16)v.w};
      *(f16x4*)&dq[(size_t)i * 4] = o;
    } else {
      int j = i - 196608;  // < 65536 by grid sizing
      float4 v = ((const float4*)wp)[j];
      f16x4 o = {(_Float16)v.x, (_Float16)v.y, (_Float16)v.z, (_Float16)v.w};
      *(f16x4*)&dp[(size_t)j * 4] = o;
    }
    return;
  }
  const int b = blockIdx.x & 15;
  const int g = blockIdx.x >> 4;
  const size_t base = ((size_t)(b * 512 + g * 16)) * 1024;
  const float4* xp = (const float4*)(x + base);

  float4 vals[16];
  float s = 0.f, sq = 0.f;
#pragma unroll
  for (int r = 0; r < 16; ++r) {
    float4 v = xp[tid + 256 * r];
    vals[r] = v;
    s += v.x + v.y + v.z + v.w;
    sq += v.x * v.x + v.y * v.y + v.z * v.z + v.w * v.w;
  }
  __shared__ float rs[256];
  __shared__ float rq[256];
  rs[tid] = s;
  rq[tid] = sq;
  __syncthreads();
  for (int off = 128; off > 0; off >>= 1) {
    if (tid < off) {
      rs[tid] += rs[tid + off];
      rq[tid] += rq[tid + off];
    }
    __syncthreads();
  }
  const float mean = rs[0] * (1.f / 16384.f);
  const float var = rq[0] * (1.f / 16384.f) - mean * mean;
  const float rinv = rsqrtf(var + 1e-5f);
#pragma unroll
  for (int r = 0; r < 16; ++r) {
    const int c = g * 16 + r;
    const float wc = gw[c] * rinv;
    const float bc = gb[c] - mean * wc;
    vals[r].x = vals[r].x * wc + bc;
    vals[r].y = vals[r].y * wc + bc;
    vals[r].z = vals[r].z * wc + bc;
    vals[r].w = vals[r].w * wc + bc;
  }
  _Float16* hb = hT + ((size_t)b * 1024 + tid * 4) * 512 + g * 16;
#pragma unroll
  for (int li = 0; li < 4; ++li) {
    f16x8 o0, o1;
#pragma unroll
    for (int r = 0; r < 8; ++r) {
      float v0 = li == 0 ? vals[r].x : li == 1 ? vals[r].y
                 : li == 2 ? vals[r].z : vals[r].w;
      float v1 = li == 0 ? vals[8 + r].x : li == 1 ? vals[8 + r].y
                 : li == 2 ? vals[8 + r].z : vals[8 + r].w;
      o0[r] = (_Float16)v0;
      o1[r] = (_Float16)v1;
    }
    *(f16x8*)(hb + (size_t)li * 512) = o0;
    *(f16x8*)(hb + (size_t)li * 512 + 8) = o1;
  }
}

// ------------------------- fp16 MFMA GEMM, BK=64 single buffer --------------
// C[m][n] = sum_k A[m][k]*B[n][k] (+bias), stored TRANSPOSED: Out[n][m].
// 128x128 tile, BK=64, 8 K-steps (K=512). LDS rows are 128B linear (async
// copy needs contiguous dest); bank uniformity via XOR source swizzle:
// LDS phys 16B-chunk p of row r holds logical chunk p ^ (r&7); fragment
// reads apply the same XOR.
// Epilogue: C-frags (+bias) -> LDS [n][m] tile -> coalesced row stores.
template <typename OutT, bool BIAS_ON_M>
__global__ __launch_bounds__(256) void gemm_tn(
    const _Float16* __restrict__ A, const _Float16* __restrict__ B,
    const float* __restrict__ bias, OutT* __restrict__ Out,
    int M, int N, int K, long sA, long sB) {
  // smem: As(16K) Bs(16K) = 32K | epilogue T (34.8K)
  __shared__ __align__(16) char smem[34816];
  _Float16* As = (_Float16*)smem;
  _Float16* Bs = As + 128 * 64;
  const int tid = threadIdx.x;
  const int w = tid >> 6, lane = tid & 63;
  const int lx = lane & 15, quad = lane >> 4;
  const int wm = w >> 1, wn = w & 1;
  const int bn = blockIdx.x * 128, bm = blockIdx.y * 128;
  const int z = blockIdx.z;

  // staging geometry: row = w*32 + j*8 + (lane>>3); phys chunk = lane&7;
  // global logical chunk = (lane&7) ^ ((lane>>3)&7)  [row&7 == (lane>>3)&7]
  const int srow = w * 32 + (lane >> 3);
  const int scol = (((lane & 7) ^ ((lane >> 3) & 7)) * 8);
  const _Float16* Ag = A + (size_t)z * sA + (size_t)(bm + srow) * K + scol;
  const _Float16* Bg = B + (size_t)z * sB + (size_t)(bn + srow) * K + scol;

  f32x4 acc[4][4];
#pragma unroll
  for (int i = 0; i < 4; ++i)
#pragma unroll
    for (int j = 0; j < 4; ++j) acc[i][j] = (f32x4){0.f, 0.f, 0.f, 0.f};

  const int xa = lx & 7;  // row&7 for this lane's fragment rows

  for (int k0 = 0; k0 < K; k0 += 64) {
    __syncthreads();  // prior step's fragment reads complete
#pragma unroll
    for (int j = 0; j < 4; ++j) {
      async_cp16(Ag + (size_t)j * 8 * K + k0, &As[(w * 32 + j * 8) * 64]);
      async_cp16(Bg + (size_t)j * 8 * K + k0, &Bs[(w * 32 + j * 8) * 64]);
    }
    __syncthreads();  // implicit vmcnt(0): buffer ready
#pragma unroll
    for (int h = 0; h < 2; ++h) {
      f16x8 af[4], bf[4];
#pragma unroll
      for (int mt = 0; mt < 4; ++mt)
        af[mt] = *(const f16x8*)&As[(wm * 64 + mt * 16 + lx) * 64 +
                                    ((h * 4 + quad) ^ xa) * 8];
#pragma unroll
      for (int nt = 0; nt < 4; ++nt)
        bf[nt] = *(const f16x8*)&Bs[(wn * 64 + nt * 16 + lx) * 64 +
                                    ((h * 4 + quad) ^ xa) * 8];
#pragma unroll
      for (int mt = 0; mt < 4; ++mt)
#pragma unroll
        for (int nt = 0; nt < 4; ++nt)
          acc[mt][nt] = __builtin_amdgcn_mfma_f32_16x16x32_f16(
              af[mt], bf[nt], acc[mt][nt], 0, 0, 0);
    }
  }
  __syncthreads();  // last fragment reads done before epilogue reuses smem

  OutT* Ob = Out + (size_t)z * M * N;
  if constexpr (sizeof(OutT) == 2) {
    // ---- f16 out: single-pass 128x128 transpose tile, stride 136 ----
    _Float16* T = (_Float16*)smem;
#pragma unroll
    for (int mt = 0; mt < 4; ++mt) {
      const int m0 = bm + wm * 64 + mt * 16 + quad * 4;
      float bm4[4];
#pragma unroll
      for (int i = 0; i < 4; ++i) bm4[i] = BIAS_ON_M ? bias[m0 + i] : 0.f;
#pragma unroll
      for (int nt = 0; nt < 4; ++nt) {
        const int nl = wn * 64 + nt * 16 + lx;
        const float bn1 = BIAS_ON_M ? 0.f : bias[bn + nl];
        f16x4 o = {(_Float16)(acc[mt][nt][0] + (BIAS_ON_M ? bm4[0] : bn1)),
                   (_Float16)(acc[mt][nt][1] + (BIAS_ON_M ? bm4[1] : bn1)),
                   (_Float16)(acc[mt][nt][2] + (BIAS_ON_M ? bm4[2] : bn1)),
                   (_Float16)(acc[mt][nt][3] + (BIAS_ON_M ? bm4[3] : bn1))};
        *(f16x4*)&T[nl * 136 + wm * 64 + mt * 16 + quad * 4] = o;
      }
    }
    __syncthreads();
#pragma unroll
    for (int j = 0; j < 8; ++j) {
      const int r = j * 16 + (tid >> 4), slot = tid & 15;
      f16x8 vv = *(const f16x8*)&T[r * 136 + slot * 8];
      *(f16x8*)((_Float16*)Ob + (size_t)(bn + r) * M + bm + slot * 8) = vv;
    }
  } else {
    // ---- f32 out: two half-passes (64 n-rows each), stride 136 ----
    float* T32 = (float*)smem;
#pragma unroll
    for (int p = 0; p < 2; ++p) {
      __syncthreads();
      if (wn == p) {
#pragma unroll
        for (int mt = 0; mt < 4; ++mt) {
          const int m0 = bm + wm * 64 + mt * 16 + quad * 4;
          float bm4[4];
#pragma unroll
          for (int i = 0; i < 4; ++i) bm4[i] = BIAS_ON_M ? bias[m0 + i] : 0.f;
#pragma unroll
          for (int nt = 0; nt < 4; ++nt) {
            const int nl = nt * 16 + lx;
            const float bn1 = BIAS_ON_M ? 0.f : bias[bn + p * 64 + nl];
            float4 o = {acc[mt][nt][0] + (BIAS_ON_M ? bm4[0] : bn1),
                        acc[mt][nt][1] + (BIAS_ON_M ? bm4[1] : bn1),
                        acc[mt][nt][2] + (BIAS_ON_M ? bm4[2] : bn1),
                        acc[mt][nt][3] + (BIAS_ON_M ? bm4[3] : bn1)};
            *(float4*)&T32[nl * 136 + wm * 64 + mt * 16 + quad * 4] = o;
          }
        }
      }
      __syncthreads();
#pragma unroll
      for (int j = 0; j < 8; ++j) {
        const int r = j * 8 + (tid >> 5), slot = tid & 31;
        float4 vv = *(const float4*)&T32[r * 136 + slot * 4];
        *(float4*)((float*)Ob + (size_t)(bn + p * 64 + r) * M + bm + slot * 4) =
            vv;
      }
    }
  }
}

// ------------------------- fp16 MFMA flash attention ------------------------
// qkvT layout: [b][l][o], o = h*192 + {0..63 q, 64..127 k, 128..191 v}.
// Block = (b,h) x 128 t-tile, 4 waves; wave w owns t-cols w*32+{0..15,16..31}.
// Fixed-max softmax (verified R4/R5): p = exp2(S'), l lane-local, epilogue
// reduce. Grid (bh=128, t=8) pins a head's t-tiles to one XCD (K/V L2-hit).
// K staging: global_load_lds into double-buffered linear [64][64] tiles,
// XOR involution (src chunk^(row&7) / read chunk^(lx&7)), 2 issues/wave/tile.
// asyncK(cur) is drained by the barrier after V ds-writes (a full tile after
// issue -> latency hidden). V reg-staged + packed b32 scatter (transpose).
// Two barriers/tile: FROZEN (one-barrier variants regressed 2.4x, R10/R3).
#define LV 70
#define QSCALE 0.18033688011112042f  // 0.125 * log2(e)

__global__ __launch_bounds__(256) void attn_mfma(
    const _Float16* __restrict__ qkvT, _Float16* __restrict__ aT) {
  __shared__ __align__(16) _Float16 kb0[64 * 64];  // 8 KB, [s][ch] swizzled
  __shared__ __align__(16) _Float16 kb1[64 * 64];  // 8 KB
  __shared__ __align__(16) _Float16 vs[64 * LV];   // [ch][s]  8.75 KB

  const int tid = threadIdx.x;
  const int w = tid >> 6, lane = tid & 63;
  const int lx = lane & 15, quad = lane >> 4;
  const int bh = blockIdx.x, b = bh >> 3, h = bh & 7;
  const int t0 = blockIdx.y * 128;
  const _Float16* qb = qkvT + (size_t)b * 1024 * 1536 + h * 192;

  // ---- Q B-frags from global (once), scale 0.125*log2e folded in ----
  f16x8 qf[2][2];
#pragma unroll
  for (int g = 0; g < 2; ++g) {
    const _Float16* qrow = qb + (size_t)(t0 + w * 32 + g * 16 + lx) * 1536;
    qf[g][0] = *(const f16x8*)(qrow + quad * 8);
    qf[g][1] = *(const f16x8*)(qrow + 32 + quad * 8);
#pragma unroll
    for (int j = 0; j < 8; ++j) {
      qf[g][0][j] = qf[g][0][j] * (_Float16)QSCALE;
      qf[g][1][j] = qf[g][1][j] * (_Float16)QSCALE;
    }
  }

  // ---- K async staging geometry: wave w covers rows w*16..w*16+15 in two
  // 8-row (1KB) calls; lane i -> row +(i>>3), phys chunk i&7, global logical
  // chunk (i&7)^((i>>3)&7). LDS base wave-uniform. ----
  const _Float16* kgs = qb + (size_t)(w * 16 + (lane >> 3)) * 1536 + 64 +
                        (((lane & 7) ^ ((lane >> 3) & 7)) * 8);
  _Float16* const kld0 = &kb0[(w * 16) * 64];
  _Float16* const kld1 = &kb1[(w * 16) * 64];

  // ---- V staging geometry (reg path, transpose scatter) ----
  const int vs2 = (tid >> 3) * 2, vc8 = (tid & 7) * 8;  // s-pair, ch8
  const _Float16* vgp = qb + (size_t)vs2 * 1536 + 128 + vc8;

  // ---- prologue: asyncK tile0 -> kb0; V tile0 -> regs ----
  async_cp16(kgs, kld0);
  async_cp16(kgs + (size_t)8 * 1536, kld0 + 8 * 64);
  f16x8 vp0 = *(const f16x8*)vgp;
  f16x8 vp1 = *(const f16x8*)(vgp + 1536);

  float l_r[2] = {0.f, 0.f};
  f32x4 oacc[2][4];  // [g][mt]: D[m=ch: mt*16+quad*4+i][n=t: w*32+g*16+lx]
#pragma unroll
  for (int g = 0; g < 2; ++g)
#pragma unroll
    for (int mt = 0; mt < 4; ++mt) oacc[g][mt] = (f32x4){0.f, 0.f, 0.f, 0.f};

  const int xa = lx & 7;

  auto tile = [&](int s0, const _Float16* kcur, _Float16* kldn) {
    __syncthreads();  // sync1: prior tile's vs reads complete
    // ---- V regs -> vs (transposed, s-pairs packed b32) ----
#pragma unroll
    for (int i = 0; i < 8; ++i) {
      union { _Float16 hh[2]; unsigned u; } p;
      p.hh[0] = vp0[i];
      p.hh[1] = vp1[i];
      *(unsigned*)&vs[(vc8 + i) * LV + vs2] = p.u;
    }
    __syncthreads();  // sync2: vs visible; implicit vmcnt(0) lands asyncK(cur)

    // ---- issue next tile's asyncK + V reg loads (hide under compute) ----
    if (s0 + 64 < 1024) {
      async_cp16(kgs + (size_t)(s0 + 64) * 1536, kldn);
      async_cp16(kgs + (size_t)(s0 + 72) * 1536, kldn + 8 * 64);
      const _Float16* vg2 = vgp + (size_t)(s0 + 64) * 1536;
      vp0 = *(const f16x8*)vg2;
      vp1 = *(const f16x8*)(vg2 + 1536);
    }

    // ---- S^T[s][t] both groups; K-frags read once per sb ----
    f32x4 sf[2][4];
#pragma unroll
    for (int sb = 0; sb < 4; ++sb) {
      f16x8 k0 = *(const f16x8*)&kcur[(sb * 16 + lx) * 64 + ((quad ^ xa) * 8)];
      f16x8 k1 =
          *(const f16x8*)&kcur[(sb * 16 + lx) * 64 + (((4 + quad) ^ xa) * 8)];
#pragma unroll
      for (int g = 0; g < 2; ++g) {
        f32x4 z = {0.f, 0.f, 0.f, 0.f};
        z = __builtin_amdgcn_mfma_f32_16x16x32_f16(k0, qf[g][0], z, 0, 0, 0);
        sf[g][sb] =
            __builtin_amdgcn_mfma_f32_16x16x32_f16(k1, qf[g][1], z, 0, 0, 0);
      }
    }

    // ---- softmax-lite: p = exp2(S'), packed cvt, lane-local l ----
    f16x4 pf[2][4];
#pragma unroll
    for (int g = 0; g < 2; ++g) {
      float sum = 0.f;
#pragma unroll
      for (int sb = 0; sb < 4; ++sb) {
        float p0 = __builtin_amdgcn_exp2f(sf[g][sb][0]);
        float p1 = __builtin_amdgcn_exp2f(sf[g][sb][1]);
        float p2 = __builtin_amdgcn_exp2f(sf[g][sb][2]);
        float p3 = __builtin_amdgcn_exp2f(sf[g][sb][3]);
        sum += (p0 + p1) + (p2 + p3);
        union { fp16x2 h2[2]; f16x4 h4; } pk;
        pk.h2[0] = __builtin_amdgcn_cvt_pkrtz(p0, p1);
        pk.h2[1] = __builtin_amdgcn_cvt_pkrtz(p2, p3);
        pf[g][sb] = pk.h4;
      }
      l_r[g] += sum;
    }

    // ---- PV: V-frag read once serves both groups ----
#pragma unroll
    for (int kb = 0; kb < 4; ++kb)
#pragma unroll
      for (int mt = 0; mt < 4; ++mt) {
        f16x4 vf = *(const f16x4*)&vs[(mt * 16 + lx) * LV + kb * 16 + quad * 4];
        oacc[0][mt] = MFMA_K16(vf, pf[0][kb], oacc[0][mt]);
        oacc[1][mt] = MFMA_K16(vf, pf[1][kb], oacc[1][mt]);
      }
  };

  for (int s0 = 0; s0 < 1024; s0 += 128) {
    tile(s0, kb0, kld1);       // compute kb0, stage next into kb1
    tile(s0 + 64, kb1, kld0);  // compute kb1, stage next into kb0
  }

  // ---- epilogue: reduce l across quads once; aT[b][t][h*64+ch] = O/l ----
#pragma unroll
  for (int g = 0; g < 2; ++g) {
    float l = l_r[g];
    l += __shfl_xor(l, 16);
    l += __shfl_xor(l, 32);
    const float linv = 1.f / l;
    _Float16* ob =
        aT + ((size_t)b * 1024 + t0 + w * 32 + g * 16 + lx) * 512 + h * 64;
#pragma unroll
    for (int mt = 0; mt < 4; ++mt) {
      f16x4 o = {(_Float16)(oacc[g][mt][0] * linv),
                 (_Float16)(oacc[g][mt][1] * linv),
                 (_Float16)(oacc[g][mt][2] * linv),
                 (_Float16)(oacc[g][mt][3] * linv)};
      *(f16x4*)&ob[mt * 16 + quad * 4] = o;
    }
  }
}

// ---------------------------------------------------------------------------
extern "C" void kernel_launch(void* const* d_in, const int* in_sizes, int n_in,
                              void* d_out, int out_size, void* d_ws,
                              size_t ws_size, hipStream_t stream) {
  const float* x = (const float*)d_in[0];
  const float* norm_w = (const float*)d_in[1];
  const float* norm_b = (const float*)d_in[2];
  const float* w_qkv = (const float*)d_in[3];
  const float* b_qkv = (const float*)d_in[4];
  const float* w_proj = (const float*)d_in[5];
  const float* b_proj = (const float*)d_in[6];
  float* out = (float*)d_out;

  _Float16* hT = (_Float16*)d_ws;
  _Float16* qkvT = hT + (size_t)16 * 1024 * 512;
  _Float16* wq = qkvT + (size_t)16 * 1024 * 1536;
  _Float16* wp = wq + (size_t)1536 * 512;
  _Float16* aT = hT;

  gn_cvt<<<1536, 256, 0, stream>>>(x, norm_w, norm_b, hT, w_qkv, w_proj, wq,
                                   wp);
  gemm_tn<_Float16, true><<<dim3(8, 12, 16), 256, 0, stream>>>(
      wq, hT, b_qkv, qkvT, 1536, 1024, 512, 0L, 524288L);
  attn_mfma<<<dim3(128, 8), 256, 0, stream>>>(qkvT, aT);
  gemm_tn<float, false><<<dim3(4, 8, 16), 256, 0, stream>>>(
      aT, wp, b_proj, out, 1024, 512, 512, 524288L, 0L);
}